// Round 1
// baseline (237.856 us; speedup 1.0000x reference)
//
#include <hip/hip_runtime.h>
#include <math.h>

// Problem constants (from reference)
#define BB 32
#define TT 4096
#define NN 11
#define FF 16
#define HH 32
#define LN_EPS 1e-5f

// total (token, m) work items = B*T*N = 1,441,792 = 5632 * 256
#define TOTAL_ITEMS (BB * TT * NN)

__global__ __launch_bounds__(256) void fused_proj_mlp_kernel(
    const float* __restrict__ x,        // [B,T,N,F]
    const int*   __restrict__ lab_idx,  // [B]
    const float* __restrict__ proj,     // [L,N,N]  (n,m)
    const float* __restrict__ bias,     // [L,1,N,F]
    const float* __restrict__ w1,       // [F,H]
    const float* __restrict__ b1,       // [H]
    const float* __restrict__ ln_g,     // [H]
    const float* __restrict__ ln_b,     // [H]
    const float* __restrict__ w2,       // [H,F]
    const float* __restrict__ b2,       // [F]
    float*       __restrict__ out)      // [B,T,N,F]
{
    const unsigned w = blockIdx.x * 256u + threadIdx.x;
    if (w >= TOTAL_ITEMS) return;

    const unsigned token = w / 11u;          // magic-mul division
    const unsigned m     = w - token * 11u;  // station index (output row)
    const unsigned b     = token >> 12;      // token / T  (T = 4096)
    const int lab = lab_idx[b];

    // ---- projection: o[f] = sum_n x[token,n,f] * proj[lab,n,m] + bias[lab,0,m,f]
    const float4* xp4 = reinterpret_cast<const float4*>(x) + (size_t)token * (NN * FF / 4);
    const float*  Wp  = proj + (size_t)lab * (NN * NN) + m;            // stride 11 over n
    const float4* bp4 = reinterpret_cast<const float4*>(bias) + (size_t)lab * (NN * FF / 4) + m * (FF / 4);

    float o[FF];
    #pragma unroll
    for (int f4 = 0; f4 < FF / 4; ++f4) {
        float4 v = bp4[f4];
        o[f4 * 4 + 0] = v.x; o[f4 * 4 + 1] = v.y;
        o[f4 * 4 + 2] = v.z; o[f4 * 4 + 3] = v.w;
    }
    #pragma unroll
    for (int n = 0; n < NN; ++n) {
        const float wnm = Wp[n * NN];
        #pragma unroll
        for (int f4 = 0; f4 < FF / 4; ++f4) {
            float4 v = xp4[n * (FF / 4) + f4];
            o[f4 * 4 + 0] = fmaf(v.x, wnm, o[f4 * 4 + 0]);
            o[f4 * 4 + 1] = fmaf(v.y, wnm, o[f4 * 4 + 1]);
            o[f4 * 4 + 2] = fmaf(v.z, wnm, o[f4 * 4 + 2]);
            o[f4 * 4 + 3] = fmaf(v.w, wnm, o[f4 * 4 + 3]);
        }
    }

    // ---- h = o @ w1 + b1   (w1 indices are unroll-constant + uniform ptr -> s_load)
    float h[HH];
    #pragma unroll
    for (int j = 0; j < HH; ++j) h[j] = b1[j];
    #pragma unroll
    for (int f = 0; f < FF; ++f) {
        const float xf = o[f];
        #pragma unroll
        for (int j = 0; j < HH; ++j) h[j] = fmaf(xf, w1[f * HH + j], h[j]);
    }

    // ---- LayerNorm over H
    float s = 0.f, ss = 0.f;
    #pragma unroll
    for (int j = 0; j < HH; ++j) { s += h[j]; ss += h[j] * h[j]; }
    const float mu   = s * (1.f / HH);
    const float var  = ss * (1.f / HH) - mu * mu;
    const float rstd = rsqrtf(var + LN_EPS);

    // ---- affine + exact GELU
    #pragma unroll
    for (int j = 0; j < HH; ++j) {
        float v = (h[j] - mu) * rstd * ln_g[j] + ln_b[j];
        h[j] = 0.5f * v * (1.f + erff(v * 0.70710678118654752f));
    }

    // ---- o2 = h @ w2 + b2
    float o2[FF];
    #pragma unroll
    for (int f = 0; f < FF; ++f) o2[f] = b2[f];
    #pragma unroll
    for (int j = 0; j < HH; ++j) {
        const float hj = h[j];
        #pragma unroll
        for (int f = 0; f < FF; ++f) o2[f] = fmaf(hj, w2[j * FF + f], o2[f]);
    }

    // ---- store 64 contiguous bytes at out + w*16 floats
    float4* op4 = reinterpret_cast<float4*>(out) + (size_t)w * (FF / 4);
    #pragma unroll
    for (int f4 = 0; f4 < FF / 4; ++f4) {
        op4[f4] = make_float4(o2[f4 * 4 + 0], o2[f4 * 4 + 1],
                              o2[f4 * 4 + 2], o2[f4 * 4 + 3]);
    }
}

extern "C" void kernel_launch(void* const* d_in, const int* in_sizes, int n_in,
                              void* d_out, int out_size, void* d_ws, size_t ws_size,
                              hipStream_t stream) {
    const float* x       = (const float*)d_in[0];
    const int*   lab_idx = (const int*)  d_in[1];
    const float* proj    = (const float*)d_in[2];
    const float* bias    = (const float*)d_in[3];
    const float* w1      = (const float*)d_in[4];
    const float* b1      = (const float*)d_in[5];
    const float* ln_g    = (const float*)d_in[6];
    const float* ln_b    = (const float*)d_in[7];
    const float* w2      = (const float*)d_in[8];
    const float* b2      = (const float*)d_in[9];
    float* out = (float*)d_out;

    const int blocks = (TOTAL_ITEMS + 255) / 256;  // 5632
    fused_proj_mlp_kernel<<<blocks, 256, 0, stream>>>(
        x, lab_idx, proj, bias, w1, b1, ln_g, ln_b, w2, b2, out);
}